// Round 2
// baseline (264.078 us; speedup 1.0000x reference)
//
#include <hip/hip_runtime.h>
#include <hip/hip_bf16.h>
#include <math.h>

typedef __bf16 bf16;
typedef __attribute__((ext_vector_type(8))) __bf16 bf16x8;
typedef __attribute__((ext_vector_type(4))) __bf16 bf16x4;
typedef __attribute__((ext_vector_type(4))) float f32x4;

#define LOG2E 1.4426950408889634f

__device__ __forceinline__ void gload16(const bf16* g, bf16* l) {
  __builtin_amdgcn_global_load_lds(
      (const __attribute__((address_space(1))) void*)g,
      (__attribute__((address_space(3))) void*)l, 16, 0, 0);
}

// ---------------------------------------------------------------- cast fp32 -> bf16
__global__ void cast_kernel(const float* __restrict__ src, bf16* __restrict__ dst, int n4) {
  int i = blockIdx.x * blockDim.x + threadIdx.x;
  int stride = gridDim.x * blockDim.x;
  for (; i < n4; i += stride) {
    float4 v = ((const float4*)src)[i];
    bf16x4 o = { (bf16)v.x, (bf16)v.y, (bf16)v.z, (bf16)v.w };
    ((bf16x4*)dst)[i] = o;
  }
}

// ---------------------------------------------------------------- V transpose: qkv V-part -> vt[(b*8+h)*96+hd][2048]
__launch_bounds__(256)
__global__ void vtrans_kernel(const bf16* __restrict__ qkv, bf16* __restrict__ vt) {
  __shared__ bf16 T[96][72];
  const int t = threadIdx.x;
  const int tk0 = blockIdx.x * 64;
  const int h = blockIdx.y, b = blockIdx.z;
  const bf16* vp = qkv + ((size_t)b * 2048 + tk0) * 2304 + 1536 + h * 96;
  const int row = t >> 2;            // token 0..63
  const int cb = (t & 3) * 24;       // hd col base
#pragma unroll
  for (int i = 0; i < 3; i++) {
    bf16x8 v = *(const bf16x8*)(vp + (size_t)row * 2304 + cb + i * 8);
#pragma unroll
    for (int j = 0; j < 8; j++) T[cb + i * 8 + j][row] = v[j];
  }
  __syncthreads();
  bf16* op = vt + (size_t)((b * 8 + h) * 96) * 2048 + tk0;
#pragma unroll
  for (int i = 0; i < 3; i++) {
    int hd = (t >> 3) + i * 32;
    int tk = (t & 7) * 8;
    *(bf16x8*)(op + (size_t)hd * 2048 + tk) = *(const bf16x8*)&T[hd][tk];
  }
}

// ---------------------------------------------------------------- GEMM (m97 structure): C = A @ W^T (+bias)(+res)(+gelu)
// A [N,K] bf16, W [O,K] bf16. Staging via global_load_lds width-16, linear LDS.
// MODE 0: out bf16 = acc + bias ; MODE 1: out f32 = acc+bias+res ; MODE 2: out bf16 = gelu_erf(acc+bias)
template<int MODE>
__launch_bounds__(256)
__global__ void gemm_kernel(const bf16* __restrict__ A, const bf16* __restrict__ W,
                            const float* __restrict__ bias, const float* __restrict__ res,
                            void* __restrict__ out, int K, int O) {
  __shared__ bf16 As[128 * 64];
  __shared__ bf16 Bs[128 * 64];
  const int t    = threadIdx.x;
  const int lane = t & 63;
  const int wave = t >> 6;
  const int wr = (wave >> 1) * 64;
  const int wc = (wave & 1) * 64;
  const int n0 = blockIdx.y * 128;
  const int o0 = blockIdx.x * 128;

  f32x4 zero = {0.f, 0.f, 0.f, 0.f};
  f32x4 acc[4][4];
#pragma unroll
  for (int m = 0; m < 4; m++)
#pragma unroll
    for (int n = 0; n < 4; n++) acc[m][n] = zero;

  const int fr  = lane & 15;
  const int fg8 = (lane >> 4) * 8;

  for (int k0 = 0; k0 < K; k0 += 64) {
    __syncthreads();
#pragma unroll
    for (int c = 0; c < 4; c++) {
      int f = c * 256 + t;
      int row = f >> 3;
      int col = (f & 7) * 8;
      gload16(&A[(size_t)(n0 + row) * K + k0 + col], &As[f * 8]);
      gload16(&W[(size_t)(o0 + row) * K + k0 + col], &Bs[f * 8]);
    }
    __syncthreads();
#pragma unroll
    for (int kf = 0; kf < 2; kf++) {
      bf16x8 a[4], b[4];
#pragma unroll
      for (int m = 0; m < 4; m++) a[m] = *(const bf16x8*)&As[(wr + m * 16 + fr) * 64 + kf * 32 + fg8];
#pragma unroll
      for (int n = 0; n < 4; n++) b[n] = *(const bf16x8*)&Bs[(wc + n * 16 + fr) * 64 + kf * 32 + fg8];
#pragma unroll
      for (int m = 0; m < 4; m++)
#pragma unroll
        for (int n = 0; n < 4; n++)
          acc[m][n] = __builtin_amdgcn_mfma_f32_16x16x32_bf16(a[m], b[n], acc[m][n], 0, 0, 0);
    }
  }

  const int fg4 = (lane >> 4) * 4;
#pragma unroll
  for (int m = 0; m < 4; m++) {
#pragma unroll
    for (int n = 0; n < 4; n++) {
      int col = o0 + wc + n * 16 + fr;
      float bv = bias[col];
#pragma unroll
      for (int r = 0; r < 4; r++) {
        int row = n0 + wr + m * 16 + fg4 + r;
        float v = acc[m][n][r] + bv;
        if constexpr (MODE == 1) {
          v += res[(size_t)row * O + col];
          ((float*)out)[(size_t)row * O + col] = v;
        } else if constexpr (MODE == 2) {
          v = 0.5f * v * (1.0f + erff(v * 0.70710678118654752f));
          ((bf16*)out)[(size_t)row * O + col] = (bf16)v;
        } else {
          ((bf16*)out)[(size_t)row * O + col] = (bf16)v;
        }
      }
    }
  }
}

// ---------------------------------------------------------------- flash attention
// 8 waves x 16 q-rows = 128 q/block. KV tile 64, double-buffered LDS, 1 barrier/iter,
// async reg-staged prefetch (T14), pre-transposed V, bf16 bias, defer-max (T13).
__launch_bounds__(512, 2)
__global__ void attn_kernel(const bf16* __restrict__ qkv, const bf16* __restrict__ vt,
                            const bf16* __restrict__ biasb, bf16* __restrict__ ctx) {
  __shared__ bf16 Ks[2][64][104];   // 208B stride: fq*52w -> 2-way max
  __shared__ bf16 Vs[2][96][72];    // 144B stride: fq*36w -> 2-way max
  __shared__ bf16 Pl[8][16][72];
  const int t    = threadIdx.x;
  const int lane = t & 63;
  const int wave = t >> 6;
  const int qb = blockIdx.x, h = blockIdx.y, b = blockIdx.z;
  const int q0 = qb * 128 + wave * 16;
  const int fq = lane & 15;
  const int g  = lane >> 4;
  const size_t base = (size_t)b * 2048 * 2304;

  // Q fragments (pre-loaded, reused all iters)
  bf16x8 qf[3];
  {
    const bf16* qp = qkv + base + (size_t)(q0 + fq) * 2304 + h * 96;
#pragma unroll
    for (int f = 0; f < 3; f++) qf[f] = *(const bf16x8*)(qp + f * 32 + g * 8);
  }

  // staging geometry (512 threads)
  const int kr1 = t >> 3, kc1 = (t & 7) * 8;         // K: rows 0..63, cols 0..63
  const int kr2 = t >> 2, kc2 = 64 + (t & 3) * 8;    // K (t<256): cols 64..95
  const int vr2 = 64 + (t >> 3);                      // V (t<256): hd 64..95
  const bf16* kbase = qkv + base + 768 + h * 96;
  const bf16* vbase = vt + (size_t)((b * 8 + h) * 96) * 2048;

  bf16x8 kreg0, kreg1, vreg0, vreg1;
  const bool lo = (t < 256);

  // prologue: load tile 0 into regs
  {
    kreg0 = *(const bf16x8*)(kbase + (size_t)kr1 * 2304 + kc1);
    vreg0 = *(const bf16x8*)(vbase + (size_t)kr1 * 2048 + kc1);
    if (lo) {
      kreg1 = *(const bf16x8*)(kbase + (size_t)kr2 * 2304 + kc2);
      vreg1 = *(const bf16x8*)(vbase + (size_t)vr2 * 2048 + kc1);
    }
  }

  float m_run = -1e30f, l_run = 0.f;
  f32x4 zero = {0.f, 0.f, 0.f, 0.f};
  f32x4 o_acc[6];
#pragma unroll
  for (int i = 0; i < 6; i++) o_acc[i] = zero;

  const float scale = 0.10206207261596575f;  // 1/sqrt(96)
  const bf16* bp = biasb + ((size_t)b * 2048 + q0 + fq) * 2048;

  int cur = 0;
  for (int kv0 = 0; kv0 < 2048; kv0 += 64) {
    // write staged regs -> LDS[cur]
    *(bf16x8*)&Ks[cur][kr1][kc1] = kreg0;
    *(bf16x8*)&Vs[cur][kr1][kc1] = vreg0;
    if (lo) {
      *(bf16x8*)&Ks[cur][kr2][kc2] = kreg1;
      *(bf16x8*)&Vs[cur][vr2][kc1] = vreg1;
    }
    __syncthreads();

    // async prefetch next tile into regs (hidden under compute)
    if (kv0 + 64 < 2048) {
      int nx = kv0 + 64;
      kreg0 = *(const bf16x8*)(kbase + (size_t)(nx + kr1) * 2304 + kc1);
      vreg0 = *(const bf16x8*)(vbase + (size_t)kr1 * 2048 + nx + kc1);
      if (lo) {
        kreg1 = *(const bf16x8*)(kbase + (size_t)(nx + kr2) * 2304 + kc2);
        vreg1 = *(const bf16x8*)(vbase + (size_t)vr2 * 2048 + nx + kc1);
      }
    }

    // bias for this tile
    bf16x4 bb[4];
#pragma unroll
    for (int kvt = 0; kvt < 4; kvt++)
      bb[kvt] = *(const bf16x4*)(bp + kv0 + kvt * 16 + g * 4);

    // S^T tile: lane holds q=fq, kv = kvt*16 + g*4 + r
    f32x4 s[4];
#pragma unroll
    for (int kvt = 0; kvt < 4; kvt++) {
      s[kvt] = zero;
#pragma unroll
      for (int f = 0; f < 3; f++) {
        bf16x8 kfr = *(const bf16x8*)&Ks[cur][kvt * 16 + fq][f * 32 + g * 8];
        s[kvt] = __builtin_amdgcn_mfma_f32_16x16x32_bf16(kfr, qf[f], s[kvt], 0, 0, 0);
      }
    }

    // softmax with defer-max
    float p[4][4];
    float vmax = -1e30f;
#pragma unroll
    for (int kvt = 0; kvt < 4; kvt++) {
#pragma unroll
      for (int r = 0; r < 4; r++) {
        float sv = s[kvt][r] * scale + (float)bb[kvt][r];
        p[kvt][r] = sv;
        vmax = fmaxf(vmax, sv);
      }
    }
    vmax = fmaxf(vmax, __shfl_xor(vmax, 16));
    vmax = fmaxf(vmax, __shfl_xor(vmax, 32));
    if (!__all(vmax <= m_run + 8.0f)) {
      float m_new = fmaxf(m_run, vmax);
      float corr = exp2f((m_run - m_new) * LOG2E);
      l_run *= corr;
#pragma unroll
      for (int i = 0; i < 6; i++)
#pragma unroll
        for (int r = 0; r < 4; r++) o_acc[i][r] *= corr;
      m_run = m_new;
    }
    float rsum = 0.f;
#pragma unroll
    for (int kvt = 0; kvt < 4; kvt++) {
      bf16x4 pb;
#pragma unroll
      for (int r = 0; r < 4; r++) {
        float pv = exp2f((p[kvt][r] - m_run) * LOG2E);
        rsum += pv;
        pb[r] = (bf16)pv;
      }
      *(bf16x4*)&Pl[wave][fq][kvt * 16 + g * 4] = pb;
    }
    rsum += __shfl_xor(rsum, 16);
    rsum += __shfl_xor(rsum, 32);
    l_run += rsum;

    // PV: ctx^T += V^T * P
#pragma unroll
    for (int kf = 0; kf < 2; kf++) {
      bf16x8 pfrag = *(const bf16x8*)&Pl[wave][fq][kf * 32 + g * 8];
#pragma unroll
      for (int ht = 0; ht < 6; ht++) {
        bf16x8 vfrag = *(const bf16x8*)&Vs[cur][ht * 16 + fq][kf * 32 + g * 8];
        o_acc[ht] = __builtin_amdgcn_mfma_f32_16x16x32_bf16(vfrag, pfrag, o_acc[ht], 0, 0, 0);
      }
    }
    cur ^= 1;
  }

  // epilogue: lane holds ctx^T[hd = ht*16 + g*4 + r][q = fq]
  float inv = 1.0f / l_run;
  bf16* cp = ctx + ((size_t)b * 2048 + q0 + fq) * 768 + h * 96;
#pragma unroll
  for (int ht = 0; ht < 6; ht++) {
    bf16x4 ov;
#pragma unroll
    for (int r = 0; r < 4; r++) ov[r] = (bf16)(o_acc[ht][r] * inv);
    *(bf16x4*)(cp + ht * 16 + g * 4) = ov;
  }
}

// ---------------------------------------------------------------- LayerNorm (row = block); in may alias outf
__launch_bounds__(256)
__global__ void ln_kernel(const float* in, const float* __restrict__ gamma,
                          const float* __restrict__ beta, float* outf, bf16* outb) {
  const int row = blockIdx.x;
  const int t = threadIdx.x;
  const float* rp = in + (size_t)row * 768;
  float v[3];
#pragma unroll
  for (int i = 0; i < 3; i++) v[i] = rp[t + 256 * i];
  float s = v[0] + v[1] + v[2];
  float ss = v[0] * v[0] + v[1] * v[1] + v[2] * v[2];
#pragma unroll
  for (int off = 1; off < 64; off <<= 1) {
    s += __shfl_xor(s, off);
    ss += __shfl_xor(ss, off);
  }
  __shared__ float red[8];
  if ((t & 63) == 0) { red[(t >> 6) * 2] = s; red[(t >> 6) * 2 + 1] = ss; }
  __syncthreads();
  s = red[0] + red[2] + red[4] + red[6];
  ss = red[1] + red[3] + red[5] + red[7];
  float mu = s * (1.0f / 768.0f);
  float var = ss * (1.0f / 768.0f) - mu * mu;
  float rs = rsqrtf(var + 1e-5f);
#pragma unroll
  for (int i = 0; i < 3; i++) {
    int col = t + 256 * i;
    float y = (v[i] - mu) * rs * gamma[col] + beta[col];
    outf[(size_t)row * 768 + col] = y;
    if (outb) outb[(size_t)row * 768 + col] = (bf16)y;
  }
}

// ---------------------------------------------------------------- launch
extern "C" void kernel_launch(void* const* d_in, const int* in_sizes, int n_in,
                              void* d_out, int out_size, void* d_ws, size_t ws_size,
                              hipStream_t stream) {
  (void)in_sizes; (void)n_in; (void)out_size; (void)ws_size;
  const float* x     = (const float*)d_in[0];
  const float* ab    = (const float*)d_in[1];
  const float* w_qkv = (const float*)d_in[2];
  const float* b_qkv = (const float*)d_in[3];
  const float* w_out = (const float*)d_in[4];
  const float* b_out = (const float*)d_in[5];
  const float* W1    = (const float*)d_in[6];
  const float* b1    = (const float*)d_in[7];
  const float* W2    = (const float*)d_in[8];
  const float* b2    = (const float*)d_in[9];
  const float* g1    = (const float*)d_in[10];
  const float* be1   = (const float*)d_in[11];
  const float* g2    = (const float*)d_in[12];
  const float* be2   = (const float*)d_in[13];
  float* outf = (float*)d_out;

  char* p = (char*)d_ws;
  bf16* xb    = (bf16*)p;  p += (size_t)4096 * 768 * 2;
  bf16* qkv   = (bf16*)p;  p += (size_t)4096 * 2304 * 2;
  bf16* ctx   = (bf16*)p;  p += (size_t)4096 * 768 * 2;
  float* x1f  = (float*)p; p += (size_t)4096 * 768 * 4;     // aliased: vt during attn phase
  bf16* x1b   = (bf16*)p;  p += (size_t)4096 * 768 * 2;
  bf16* hbuf  = (bf16*)p;  p += (size_t)4096 * 2048 * 2;    // aliased: biasb during attn phase
  bf16* wqkvb = (bf16*)p;  p += (size_t)2304 * 768 * 2;
  bf16* woutb = (bf16*)p;  p += (size_t)768 * 768 * 2;
  bf16* w1b   = (bf16*)p;  p += (size_t)2048 * 768 * 2;
  bf16* w2b   = (bf16*)p;  p += (size_t)768 * 2048 * 2;
  bf16* vtb   = (bf16*)x1f;   // 2*8*96*2048*2 = 6.3MB <= 12.6MB
  bf16* biasb = hbuf;         // 2*2048*2048*2 = 16.78MB == 16.78MB

  cast_kernel<<<1024, 256, 0, stream>>>(x, xb, 4096 * 768 / 4);
  cast_kernel<<<512, 256, 0, stream>>>(w_qkv, wqkvb, 2304 * 768 / 4);
  cast_kernel<<<256, 256, 0, stream>>>(w_out, woutb, 768 * 768 / 4);
  cast_kernel<<<512, 256, 0, stream>>>(W1, w1b, 2048 * 768 / 4);
  cast_kernel<<<512, 256, 0, stream>>>(W2, w2b, 768 * 2048 / 4);
  cast_kernel<<<2048, 256, 0, stream>>>(ab, biasb, 2 * 2048 * 2048 / 4);

  // qkv = x @ in_proj_w^T + b
  gemm_kernel<0><<<dim3(18, 32), 256, 0, stream>>>(xb, wqkvb, b_qkv, nullptr, qkv, 768, 2304);
  // vt = V^T
  vtrans_kernel<<<dim3(32, 8, 2), 256, 0, stream>>>(qkv, vtb);
  // attention
  attn_kernel<<<dim3(16, 8, 2), 512, 0, stream>>>(qkv, vtb, biasb, ctx);
  // res1 = ctx @ out_w^T + out_b + x   (into d_out)
  gemm_kernel<1><<<dim3(6, 32), 256, 0, stream>>>(ctx, woutb, b_out, x, outf, 768, 768);
  // x1 = LN(res1)
  ln_kernel<<<4096, 256, 0, stream>>>(outf, g1, be1, x1f, x1b);
  // h = gelu(x1 @ W1^T + b1)
  gemm_kernel<2><<<dim3(16, 32), 256, 0, stream>>>(x1b, w1b, b1, nullptr, hbuf, 768, 2048);
  // res2 = h @ W2^T + b2 + x1   (into d_out)
  gemm_kernel<1><<<dim3(6, 32), 256, 0, stream>>>(hbuf, w2b, b2, x1f, outf, 2048, 768);
  // out = LN(res2), in place
  ln_kernel<<<4096, 256, 0, stream>>>(outf, g2, be2, outf, nullptr);
}

// Round 3
// 217.795 us; speedup vs baseline: 1.2125x; 1.2125x over previous
//
#include <hip/hip_runtime.h>
#include <hip/hip_bf16.h>
#include <math.h>

typedef __bf16 bf16;
typedef __attribute__((ext_vector_type(8))) __bf16 bf16x8;
typedef __attribute__((ext_vector_type(4))) __bf16 bf16x4;
typedef __attribute__((ext_vector_type(4))) float f32x4;

#define LOG2E 1.4426950408889634f

__device__ __forceinline__ void gload16(const bf16* g, bf16* l) {
  __builtin_amdgcn_global_load_lds(
      (const __attribute__((address_space(1))) void*)g,
      (__attribute__((address_space(3))) void*)l, 16, 0, 0);
}

// ---------------------------------------------------------------- fused cast fp32 -> bf16 (6 tensors, 1 launch)
struct CastSegs { const float* src[6]; bf16* dst[6]; };

__global__ void fused_cast_kernel(CastSegs segs) {
  // float4 prefix ends: x, w_qkv, w_out, W1, W2, ab
  const int e0 = 786432, e1 = 1228800, e2 = 1376256, e3 = 1769472, e4 = 2162688, e5 = 4259840;
  int i = blockIdx.x * blockDim.x + threadIdx.x;
  int stride = gridDim.x * blockDim.x;
  for (; i < e5; i += stride) {
    int s = 0, base = 0;
    if (i >= e0) { s = 1; base = e0; }
    if (i >= e1) { s = 2; base = e1; }
    if (i >= e2) { s = 3; base = e2; }
    if (i >= e3) { s = 4; base = e3; }
    if (i >= e4) { s = 5; base = e4; }
    float4 v = ((const float4*)segs.src[s])[i - base];
    bf16x4 o = { (bf16)v.x, (bf16)v.y, (bf16)v.z, (bf16)v.w };
    ((bf16x4*)segs.dst[s])[i - base] = o;
  }
}

// ---------------------------------------------------------------- V transpose: qkv V-part -> vt[(b*8+h)*96+hd][2048]
__launch_bounds__(256)
__global__ void vtrans_kernel(const bf16* __restrict__ qkv, bf16* __restrict__ vt) {
  __shared__ bf16 T[96][72];
  const int t = threadIdx.x;
  const int tk0 = blockIdx.x * 64;
  const int h = blockIdx.y, b = blockIdx.z;
  const bf16* vp = qkv + ((size_t)b * 2048 + tk0) * 2304 + 1536 + h * 96;
  const int row = t >> 2;            // token 0..63
  const int cb = (t & 3) * 24;       // hd col base
#pragma unroll
  for (int i = 0; i < 3; i++) {
    bf16x8 v = *(const bf16x8*)(vp + (size_t)row * 2304 + cb + i * 8);
#pragma unroll
    for (int j = 0; j < 8; j++) T[cb + i * 8 + j][row] = v[j];
  }
  __syncthreads();
  bf16* op = vt + (size_t)((b * 8 + h) * 96) * 2048 + tk0;
#pragma unroll
  for (int i = 0; i < 3; i++) {
    int hd = (t >> 3) + i * 32;
    int tk = (t & 7) * 8;
    *(bf16x8*)(op + (size_t)hd * 2048 + tk) = *(const bf16x8*)&T[hd][tk];
  }
}

// ---------------------------------------------------------------- GEMM 128x128 (m97 structure)
// MODE 0: out bf16 = acc + bias ; MODE 2: out bf16 = gelu_erf(acc+bias)
template<int MODE>
__launch_bounds__(256)
__global__ void gemm_kernel(const bf16* __restrict__ A, const bf16* __restrict__ W,
                            const float* __restrict__ bias, const float* __restrict__ res,
                            void* __restrict__ out, int K, int O) {
  __shared__ bf16 As[128 * 64];
  __shared__ bf16 Bs[128 * 64];
  const int t    = threadIdx.x;
  const int lane = t & 63;
  const int wave = t >> 6;
  const int wr = (wave >> 1) * 64;
  const int wc = (wave & 1) * 64;
  const int n0 = blockIdx.y * 128;
  const int o0 = blockIdx.x * 128;

  f32x4 zero = {0.f, 0.f, 0.f, 0.f};
  f32x4 acc[4][4];
#pragma unroll
  for (int m = 0; m < 4; m++)
#pragma unroll
    for (int n = 0; n < 4; n++) acc[m][n] = zero;

  const int fr  = lane & 15;
  const int fg8 = (lane >> 4) * 8;

  for (int k0 = 0; k0 < K; k0 += 64) {
    __syncthreads();
#pragma unroll
    for (int c = 0; c < 4; c++) {
      int f = c * 256 + t;
      int row = f >> 3;
      int col = (f & 7) * 8;
      gload16(&A[(size_t)(n0 + row) * K + k0 + col], &As[f * 8]);
      gload16(&W[(size_t)(o0 + row) * K + k0 + col], &Bs[f * 8]);
    }
    __syncthreads();
#pragma unroll
    for (int kf = 0; kf < 2; kf++) {
      bf16x8 a[4], b[4];
#pragma unroll
      for (int m = 0; m < 4; m++) a[m] = *(const bf16x8*)&As[(wr + m * 16 + fr) * 64 + kf * 32 + fg8];
#pragma unroll
      for (int n = 0; n < 4; n++) b[n] = *(const bf16x8*)&Bs[(wc + n * 16 + fr) * 64 + kf * 32 + fg8];
#pragma unroll
      for (int m = 0; m < 4; m++)
#pragma unroll
        for (int n = 0; n < 4; n++)
          acc[m][n] = __builtin_amdgcn_mfma_f32_16x16x32_bf16(a[m], b[n], acc[m][n], 0, 0, 0);
    }
  }

  const int fg4 = (lane >> 4) * 4;
#pragma unroll
  for (int m = 0; m < 4; m++) {
#pragma unroll
    for (int n = 0; n < 4; n++) {
      int col = o0 + wc + n * 16 + fr;
      float bv = bias[col];
#pragma unroll
      for (int r = 0; r < 4; r++) {
        int row = n0 + wr + m * 16 + fg4 + r;
        float v = acc[m][n][r] + bv;
        if constexpr (MODE == 2) {
          v = 0.5f * v * (1.0f + erff(v * 0.70710678118654752f));
          ((bf16*)out)[(size_t)row * O + col] = (bf16)v;
        } else {
          ((bf16*)out)[(size_t)row * O + col] = (bf16)v;
        }
      }
    }
  }
}

// ---------------------------------------------------------------- GEMM 64x64 (grid-filling, MODE1: f32 out = acc+bias+res)
__launch_bounds__(256)
__global__ void gemm64_kernel(const bf16* __restrict__ A, const bf16* __restrict__ W,
                              const float* __restrict__ bias, const float* __restrict__ res,
                              float* __restrict__ out, int K, int O) {
  __shared__ bf16 As[64 * 64];
  __shared__ bf16 Bs[64 * 64];
  const int t    = threadIdx.x;
  const int lane = t & 63;
  const int wave = t >> 6;
  const int wr = (wave >> 1) * 32;
  const int wc = (wave & 1) * 32;
  const int n0 = blockIdx.y * 64;
  const int o0 = blockIdx.x * 64;

  f32x4 zero = {0.f, 0.f, 0.f, 0.f};
  f32x4 acc[2][2];
#pragma unroll
  for (int m = 0; m < 2; m++)
#pragma unroll
    for (int n = 0; n < 2; n++) acc[m][n] = zero;

  const int fr  = lane & 15;
  const int fg8 = (lane >> 4) * 8;

  for (int k0 = 0; k0 < K; k0 += 64) {
    __syncthreads();
#pragma unroll
    for (int c = 0; c < 2; c++) {
      int f = c * 256 + t;
      int row = f >> 3;
      int col = (f & 7) * 8;
      gload16(&A[(size_t)(n0 + row) * K + k0 + col], &As[f * 8]);
      gload16(&W[(size_t)(o0 + row) * K + k0 + col], &Bs[f * 8]);
    }
    __syncthreads();
#pragma unroll
    for (int kf = 0; kf < 2; kf++) {
      bf16x8 a[2], b[2];
#pragma unroll
      for (int m = 0; m < 2; m++) a[m] = *(const bf16x8*)&As[(wr + m * 16 + fr) * 64 + kf * 32 + fg8];
#pragma unroll
      for (int n = 0; n < 2; n++) b[n] = *(const bf16x8*)&Bs[(wc + n * 16 + fr) * 64 + kf * 32 + fg8];
#pragma unroll
      for (int m = 0; m < 2; m++)
#pragma unroll
        for (int n = 0; n < 2; n++)
          acc[m][n] = __builtin_amdgcn_mfma_f32_16x16x32_bf16(a[m], b[n], acc[m][n], 0, 0, 0);
    }
  }

  const int fg4 = (lane >> 4) * 4;
#pragma unroll
  for (int m = 0; m < 2; m++) {
#pragma unroll
    for (int n = 0; n < 2; n++) {
      int col = o0 + wc + n * 16 + fr;
      float bv = bias[col];
#pragma unroll
      for (int r = 0; r < 4; r++) {
        int row = n0 + wr + m * 16 + fg4 + r;
        float v = acc[m][n][r] + bv + res[(size_t)row * O + col];
        out[(size_t)row * O + col] = v;
      }
    }
  }
}

// ---------------------------------------------------------------- flash attention, kv-split x2
// 8 waves x 16 q = 128 q/block; each block does 1024 kv; writes f32 partials + (m,l).
__launch_bounds__(512, 4)
__global__ void attn_kernel(const bf16* __restrict__ qkv, const bf16* __restrict__ vt,
                            const bf16* __restrict__ biasb, float* __restrict__ opart,
                            float* __restrict__ ml) {
  __shared__ bf16 Ks[2][64][104];
  __shared__ bf16 Vs[2][96][72];
  __shared__ bf16 Pl[8][16][72];
  const int t    = threadIdx.x;
  const int lane = t & 63;
  const int wave = t >> 6;
  const int qb = blockIdx.x, h = blockIdx.y;
  const int half = blockIdx.z & 1, b = blockIdx.z >> 1;
  const int kvstart = half * 1024;
  const int q0 = qb * 128 + wave * 16;
  const int fq = lane & 15;
  const int g  = lane >> 4;
  const size_t base = (size_t)b * 2048 * 2304;

  bf16x8 qf[3];
  {
    const bf16* qp = qkv + base + (size_t)(q0 + fq) * 2304 + h * 96;
#pragma unroll
    for (int f = 0; f < 3; f++) qf[f] = *(const bf16x8*)(qp + f * 32 + g * 8);
  }

  const int kr1 = t >> 3, kc1 = (t & 7) * 8;
  const int kr2 = t >> 2, kc2 = 64 + (t & 3) * 8;
  const int vr2 = 64 + (t >> 3);
  const bf16* kbase = qkv + base + (size_t)kvstart * 2304 + 768 + h * 96;
  const bf16* vbase = vt + (size_t)((b * 8 + h) * 96) * 2048 + kvstart;

  bf16x8 kreg0, kreg1, vreg0, vreg1;
  const bool lo = (t < 256);

  kreg0 = *(const bf16x8*)(kbase + (size_t)kr1 * 2304 + kc1);
  vreg0 = *(const bf16x8*)(vbase + (size_t)kr1 * 2048 + kc1);
  if (lo) {
    kreg1 = *(const bf16x8*)(kbase + (size_t)kr2 * 2304 + kc2);
    vreg1 = *(const bf16x8*)(vbase + (size_t)vr2 * 2048 + kc1);
  }

  float m_run = -1e30f, l_run = 0.f;
  f32x4 zero = {0.f, 0.f, 0.f, 0.f};
  f32x4 o_acc[6];
#pragma unroll
  for (int i = 0; i < 6; i++) o_acc[i] = zero;

  const float scale = 0.10206207261596575f;  // 1/sqrt(96)
  const bf16* bp = biasb + ((size_t)b * 2048 + q0 + fq) * 2048 + kvstart;

  int cur = 0;
  for (int kv0 = 0; kv0 < 1024; kv0 += 64) {
    *(bf16x8*)&Ks[cur][kr1][kc1] = kreg0;
    *(bf16x8*)&Vs[cur][kr1][kc1] = vreg0;
    if (lo) {
      *(bf16x8*)&Ks[cur][kr2][kc2] = kreg1;
      *(bf16x8*)&Vs[cur][vr2][kc1] = vreg1;
    }
    __syncthreads();

    if (kv0 + 64 < 1024) {
      int nx = kv0 + 64;
      kreg0 = *(const bf16x8*)(kbase + (size_t)(nx + kr1) * 2304 + kc1);
      vreg0 = *(const bf16x8*)(vbase + (size_t)kr1 * 2048 + nx + kc1);
      if (lo) {
        kreg1 = *(const bf16x8*)(kbase + (size_t)(nx + kr2) * 2304 + kc2);
        vreg1 = *(const bf16x8*)(vbase + (size_t)vr2 * 2048 + nx + kc1);
      }
    }
    __builtin_amdgcn_sched_barrier(0);  // pin prefetch issue here (don't sink to LDS-write)

    bf16x4 bb[4];
#pragma unroll
    for (int kvt = 0; kvt < 4; kvt++)
      bb[kvt] = *(const bf16x4*)(bp + kv0 + kvt * 16 + g * 4);

    f32x4 s[4];
#pragma unroll
    for (int kvt = 0; kvt < 4; kvt++) {
      s[kvt] = zero;
#pragma unroll
      for (int f = 0; f < 3; f++) {
        bf16x8 kfr = *(const bf16x8*)&Ks[cur][kvt * 16 + fq][f * 32 + g * 8];
        s[kvt] = __builtin_amdgcn_mfma_f32_16x16x32_bf16(kfr, qf[f], s[kvt], 0, 0, 0);
      }
    }

    float p[4][4];
    float vmax = -1e30f;
#pragma unroll
    for (int kvt = 0; kvt < 4; kvt++) {
#pragma unroll
      for (int r = 0; r < 4; r++) {
        float sv = s[kvt][r] * scale + (float)bb[kvt][r];
        p[kvt][r] = sv;
        vmax = fmaxf(vmax, sv);
      }
    }
    vmax = fmaxf(vmax, __shfl_xor(vmax, 16));
    vmax = fmaxf(vmax, __shfl_xor(vmax, 32));
    if (!__all(vmax <= m_run + 8.0f)) {
      float m_new = fmaxf(m_run, vmax);
      float corr = exp2f((m_run - m_new) * LOG2E);
      l_run *= corr;
#pragma unroll
      for (int i = 0; i < 6; i++)
#pragma unroll
        for (int r = 0; r < 4; r++) o_acc[i][r] *= corr;
      m_run = m_new;
    }
    float rsum = 0.f;
#pragma unroll
    for (int kvt = 0; kvt < 4; kvt++) {
      bf16x4 pb;
#pragma unroll
      for (int r = 0; r < 4; r++) {
        float pv = exp2f((p[kvt][r] - m_run) * LOG2E);
        rsum += pv;
        pb[r] = (bf16)pv;
      }
      *(bf16x4*)&Pl[wave][fq][kvt * 16 + g * 4] = pb;
    }
    rsum += __shfl_xor(rsum, 16);
    rsum += __shfl_xor(rsum, 32);
    l_run += rsum;

#pragma unroll
    for (int kf = 0; kf < 2; kf++) {
      bf16x8 pfrag = *(const bf16x8*)&Pl[wave][fq][kf * 32 + g * 8];
#pragma unroll
      for (int ht = 0; ht < 6; ht++) {
        bf16x8 vfrag = *(const bf16x8*)&Vs[cur][ht * 16 + fq][kf * 32 + g * 8];
        o_acc[ht] = __builtin_amdgcn_mfma_f32_16x16x32_bf16(vfrag, pfrag, o_acc[ht], 0, 0, 0);
      }
    }
    cur ^= 1;
  }

  // write un-normalized partials
  float* op = opart + (size_t)half * (16 * 2048 * 96) + ((size_t)(b * 8 + h) * 2048 + q0 + fq) * 96;
  float* mlp = ml + ((size_t)half * 32768 + (size_t)(b * 8 + h) * 2048 + q0 + fq) * 2;
#pragma unroll
  for (int ht = 0; ht < 6; ht++)
    *(f32x4*)&op[ht * 16 + g * 4] = o_acc[ht];
  if (g == 0) { mlp[0] = m_run; mlp[1] = l_run; }
}

// ---------------------------------------------------------------- combine kv-split partials -> ctx bf16
__launch_bounds__(256)
__global__ void attn_combine_kernel(const float* __restrict__ opart, const float* __restrict__ ml,
                                    bf16* __restrict__ ctx) {
  int idx = blockIdx.x * blockDim.x + threadIdx.x;  // float4 id, total 786432
  if (idx >= 786432) return;
  int e = idx * 4;
  int bh = e / (2048 * 96);
  int rem = e - bh * (2048 * 96);
  int q = rem / 96;
  int hd = rem - q * 96;
  const float* op0 = opart;
  const float* op1 = opart + (size_t)16 * 2048 * 96;
  float4 o1 = *(const float4*)&op0[e];
  float4 o2 = *(const float4*)&op1[e];
  const float* ml0 = ml + (size_t)(bh * 2048 + q) * 2;
  const float* ml1 = ml0 + (size_t)32768 * 2;
  float m1 = ml0[0], l1 = ml0[1];
  float m2 = ml1[0], l2 = ml1[1];
  float M = fmaxf(m1, m2);
  float w1 = exp2f((m1 - M) * LOG2E);
  float w2 = exp2f((m2 - M) * LOG2E);
  float inv = 1.0f / (l1 * w1 + l2 * w2);
  int b = bh >> 3, h = bh & 7;
  bf16x4 o;
  o[0] = (bf16)((o1.x * w1 + o2.x * w2) * inv);
  o[1] = (bf16)((o1.y * w1 + o2.y * w2) * inv);
  o[2] = (bf16)((o1.z * w1 + o2.z * w2) * inv);
  o[3] = (bf16)((o1.w * w1 + o2.w * w2) * inv);
  *(bf16x4*)&ctx[((size_t)b * 2048 + q) * 768 + h * 96 + hd] = o;
}

// ---------------------------------------------------------------- LayerNorm (row = block); in may alias outf
__launch_bounds__(256)
__global__ void ln_kernel(const float* in, const float* __restrict__ gamma,
                          const float* __restrict__ beta, float* outf, bf16* outb) {
  const int row = blockIdx.x;
  const int t = threadIdx.x;
  const float* rp = in + (size_t)row * 768;
  float v[3];
#pragma unroll
  for (int i = 0; i < 3; i++) v[i] = rp[t + 256 * i];
  float s = v[0] + v[1] + v[2];
  float ss = v[0] * v[0] + v[1] * v[1] + v[2] * v[2];
#pragma unroll
  for (int off = 1; off < 64; off <<= 1) {
    s += __shfl_xor(s, off);
    ss += __shfl_xor(ss, off);
  }
  __shared__ float red[8];
  if ((t & 63) == 0) { red[(t >> 6) * 2] = s; red[(t >> 6) * 2 + 1] = ss; }
  __syncthreads();
  s = red[0] + red[2] + red[4] + red[6];
  ss = red[1] + red[3] + red[5] + red[7];
  float mu = s * (1.0f / 768.0f);
  float var = ss * (1.0f / 768.0f) - mu * mu;
  float rs = rsqrtf(var + 1e-5f);
#pragma unroll
  for (int i = 0; i < 3; i++) {
    int col = t + 256 * i;
    float y = (v[i] - mu) * rs * gamma[col] + beta[col];
    outf[(size_t)row * 768 + col] = y;
    if (outb) outb[(size_t)row * 768 + col] = (bf16)y;
  }
}

// ---------------------------------------------------------------- launch
extern "C" void kernel_launch(void* const* d_in, const int* in_sizes, int n_in,
                              void* d_out, int out_size, void* d_ws, size_t ws_size,
                              hipStream_t stream) {
  (void)in_sizes; (void)n_in; (void)out_size; (void)ws_size;
  const float* x     = (const float*)d_in[0];
  const float* ab    = (const float*)d_in[1];
  const float* w_qkv = (const float*)d_in[2];
  const float* b_qkv = (const float*)d_in[3];
  const float* w_out = (const float*)d_in[4];
  const float* b_out = (const float*)d_in[5];
  const float* W1    = (const float*)d_in[6];
  const float* b1    = (const float*)d_in[7];
  const float* W2    = (const float*)d_in[8];
  const float* b2    = (const float*)d_in[9];
  const float* g1    = (const float*)d_in[10];
  const float* be1   = (const float*)d_in[11];
  const float* g2    = (const float*)d_in[12];
  const float* be2   = (const float*)d_in[13];
  float* outf = (float*)d_out;

  char* p = (char*)d_ws;
  bf16* xb    = (bf16*)p;  p += (size_t)4096 * 768 * 2;
  bf16* qkv   = (bf16*)p;  p += (size_t)4096 * 2304 * 2;
  bf16* ctx   = (bf16*)p;  p += (size_t)4096 * 768 * 2;
  float* x1f  = (float*)p; p += (size_t)4096 * 768 * 4;     // aliased: vt during attn phase
  bf16* x1b   = (bf16*)p;  p += (size_t)4096 * 768 * 2;
  bf16* hbuf  = (bf16*)p;  p += (size_t)4096 * 2048 * 2;    // aliased: biasb during attn phase
  bf16* wqkvb = (bf16*)p;  p += (size_t)2304 * 768 * 2;
  bf16* woutb = (bf16*)p;  p += (size_t)768 * 768 * 2;
  bf16* w1b   = (bf16*)p;  p += (size_t)2048 * 768 * 2;
  bf16* w2b   = (bf16*)p;  p += (size_t)768 * 2048 * 2;
  float* opart = (float*)p; p += (size_t)2 * 16 * 2048 * 96 * 4;  // 25.2 MB
  float* mlb   = (float*)p; p += (size_t)2 * 32768 * 2 * 4;       // 0.5 MB
  bf16* vtb   = (bf16*)x1f;   // 6.3MB <= 12.6MB
  bf16* biasb = hbuf;         // 16.78MB == 16.78MB

  CastSegs segs;
  segs.src[0] = x;     segs.dst[0] = xb;
  segs.src[1] = w_qkv; segs.dst[1] = wqkvb;
  segs.src[2] = w_out; segs.dst[2] = woutb;
  segs.src[3] = W1;    segs.dst[3] = w1b;
  segs.src[4] = W2;    segs.dst[4] = w2b;
  segs.src[5] = ab;    segs.dst[5] = biasb;
  fused_cast_kernel<<<2048, 256, 0, stream>>>(segs);

  // qkv = x @ in_proj_w^T + b
  gemm_kernel<0><<<dim3(18, 32), 256, 0, stream>>>(xb, wqkvb, b_qkv, nullptr, qkv, 768, 2304);
  // vt = V^T
  vtrans_kernel<<<dim3(32, 8, 2), 256, 0, stream>>>(qkv, vtb);
  // attention (kv-split x2) + combine
  attn_kernel<<<dim3(16, 8, 4), 512, 0, stream>>>(qkv, vtb, biasb, opart, mlb);
  attn_combine_kernel<<<3072, 256, 0, stream>>>(opart, mlb, ctx);
  // res1 = ctx @ out_w^T + out_b + x   (into d_out)
  gemm64_kernel<<<dim3(12, 64), 256, 0, stream>>>(ctx, woutb, b_out, x, outf, 768, 768);
  // x1 = LN(res1)
  ln_kernel<<<4096, 256, 0, stream>>>(outf, g1, be1, x1f, x1b);
  // h = gelu(x1 @ W1^T + b1)
  gemm_kernel<2><<<dim3(16, 32), 256, 0, stream>>>(x1b, w1b, b1, nullptr, hbuf, 768, 2048);
  // res2 = h @ W2^T + b2 + x1   (into d_out)
  gemm64_kernel<<<dim3(12, 64), 256, 0, stream>>>(hbuf, w2b, b2, x1f, outf, 2048, 768);
  // out = LN(res2), in place
  ln_kernel<<<4096, 256, 0, stream>>>(outf, g2, be2, outf, nullptr);
}

// Round 4
// 216.480 us; speedup vs baseline: 1.2199x; 1.0061x over previous
//
#include <hip/hip_runtime.h>
#include <hip/hip_bf16.h>
#include <math.h>

typedef __bf16 bf16;
typedef __attribute__((ext_vector_type(8))) __bf16 bf16x8;
typedef __attribute__((ext_vector_type(4))) __bf16 bf16x4;
typedef __attribute__((ext_vector_type(4))) float f32x4;

#define LOG2E 1.4426950408889634f

__device__ __forceinline__ void gload16(const bf16* g, bf16* l) {
  __builtin_amdgcn_global_load_lds(
      (const __attribute__((address_space(1))) void*)g,
      (__attribute__((address_space(3))) void*)l, 16, 0, 0);
}

// ---------------------------------------------------------------- fused cast fp32 -> bf16 (5 tensors, 1 launch)
struct CastSegs { const float* src[5]; bf16* dst[5]; };

__global__ void fused_cast_kernel(CastSegs segs) {
  // float4 prefix ends: x, w_qkv, w_out, W1, W2
  const int e0 = 786432, e1 = 1228800, e2 = 1376256, e3 = 1769472, e4 = 2162688;
  int i = blockIdx.x * blockDim.x + threadIdx.x;
  int stride = gridDim.x * blockDim.x;
  for (; i < e4; i += stride) {
    int s = 0, base = 0;
    if (i >= e0) { s = 1; base = e0; }
    if (i >= e1) { s = 2; base = e1; }
    if (i >= e2) { s = 3; base = e2; }
    if (i >= e3) { s = 4; base = e3; }
    float4 v = ((const float4*)segs.src[s])[i - base];
    bf16x4 o = { (bf16)v.x, (bf16)v.y, (bf16)v.z, (bf16)v.w };
    ((bf16x4*)segs.dst[s])[i - base] = o;
  }
}

// ---------------------------------------------------------------- GEMM 128x128 (m97 structure)
// MODE 0: out bf16 = acc + bias
// MODE 2: out bf16 = gelu_erf(acc + bias)
// MODE 3: qkv writer: cols <1536 -> bf16 to out; cols >=1536 (V) -> transposed to vt[(b*8+h)*96+hd][2048]
template<int MODE>
__launch_bounds__(256)
__global__ void gemm_kernel(const bf16* __restrict__ A, const bf16* __restrict__ W,
                            const float* __restrict__ bias, bf16* __restrict__ vt,
                            void* __restrict__ out, int K, int O) {
  __shared__ bf16 As[128 * 64];
  __shared__ bf16 Bs[128 * 64];
  const int t    = threadIdx.x;
  const int lane = t & 63;
  const int wave = t >> 6;
  const int wr = (wave >> 1) * 64;
  const int wc = (wave & 1) * 64;
  const int n0 = blockIdx.y * 128;
  const int o0 = blockIdx.x * 128;

  f32x4 zero = {0.f, 0.f, 0.f, 0.f};
  f32x4 acc[4][4];
#pragma unroll
  for (int m = 0; m < 4; m++)
#pragma unroll
    for (int n = 0; n < 4; n++) acc[m][n] = zero;

  const int fr  = lane & 15;
  const int fg8 = (lane >> 4) * 8;

  for (int k0 = 0; k0 < K; k0 += 64) {
    __syncthreads();
#pragma unroll
    for (int c = 0; c < 4; c++) {
      int f = c * 256 + t;
      int row = f >> 3;
      int col = (f & 7) * 8;
      gload16(&A[(size_t)(n0 + row) * K + k0 + col], &As[f * 8]);
      gload16(&W[(size_t)(o0 + row) * K + k0 + col], &Bs[f * 8]);
    }
    __syncthreads();
#pragma unroll
    for (int kf = 0; kf < 2; kf++) {
      bf16x8 a[4], b[4];
#pragma unroll
      for (int m = 0; m < 4; m++) a[m] = *(const bf16x8*)&As[(wr + m * 16 + fr) * 64 + kf * 32 + fg8];
#pragma unroll
      for (int n = 0; n < 4; n++) b[n] = *(const bf16x8*)&Bs[(wc + n * 16 + fr) * 64 + kf * 32 + fg8];
#pragma unroll
      for (int m = 0; m < 4; m++)
#pragma unroll
        for (int n = 0; n < 4; n++)
          acc[m][n] = __builtin_amdgcn_mfma_f32_16x16x32_bf16(a[m], b[n], acc[m][n], 0, 0, 0);
    }
  }

  const int fg4 = (lane >> 4) * 4;
#pragma unroll
  for (int m = 0; m < 4; m++) {
#pragma unroll
    for (int n = 0; n < 4; n++) {
      int col = o0 + wc + n * 16 + fr;
      float bv = bias[col];
      if constexpr (MODE == 3) {
        if (col >= 1536) {  // V columns: write transposed (uniform per n-group; 1536%16==0, head=96=6*16)
          int c = col - 1536;
          int h = c / 96;
          int hd = c - h * 96;
          int row0 = n0 + wr + m * 16 + fg4;
          int b = row0 >> 11;
          int token = row0 & 2047;
          bf16x4 ov;
#pragma unroll
          for (int r = 0; r < 4; r++) ov[r] = (bf16)(acc[m][n][r] + bv);
          *(bf16x4*)&vt[((size_t)((b * 8 + h) * 96 + hd)) * 2048 + token] = ov;
          continue;
        }
      }
#pragma unroll
      for (int r = 0; r < 4; r++) {
        int row = n0 + wr + m * 16 + fg4 + r;
        float v = acc[m][n][r] + bv;
        if constexpr (MODE == 2) {
          v = 0.5f * v * (1.0f + erff(v * 0.70710678118654752f));
          ((bf16*)out)[(size_t)row * O + col] = (bf16)v;
        } else {
          ((bf16*)out)[(size_t)row * O + col] = (bf16)v;
        }
      }
    }
  }
}

// ---------------------------------------------------------------- GEMM 128x64 (grid-filling): f32 out = acc + bias + res
__launch_bounds__(256)
__global__ void gemmW_kernel(const bf16* __restrict__ A, const bf16* __restrict__ W,
                             const float* __restrict__ bias, const float* __restrict__ res,
                             float* __restrict__ out, int K, int O) {
  __shared__ bf16 As[128 * 64];
  __shared__ bf16 Bs[64 * 64];
  const int t    = threadIdx.x;
  const int lane = t & 63;
  const int wave = t >> 6;
  const int wr = wave * 32;          // 4 waves stacked in M; each wave 32x64
  const int n0 = blockIdx.y * 128;
  const int o0 = blockIdx.x * 64;

  f32x4 zero = {0.f, 0.f, 0.f, 0.f};
  f32x4 acc[2][4];
#pragma unroll
  for (int m = 0; m < 2; m++)
#pragma unroll
    for (int n = 0; n < 4; n++) acc[m][n] = zero;

  const int fr  = lane & 15;
  const int fg8 = (lane >> 4) * 8;

  for (int k0 = 0; k0 < K; k0 += 64) {
    __syncthreads();
#pragma unroll
    for (int c = 0; c < 4; c++) {
      int f = c * 256 + t;
      int row = f >> 3;
      int col = (f & 7) * 8;
      gload16(&A[(size_t)(n0 + row) * K + k0 + col], &As[f * 8]);
    }
#pragma unroll
    for (int c = 0; c < 2; c++) {
      int f = c * 256 + t;
      int row = f >> 3;
      int col = (f & 7) * 8;
      gload16(&W[(size_t)(o0 + row) * K + k0 + col], &Bs[f * 8]);
    }
    __syncthreads();
#pragma unroll
    for (int kf = 0; kf < 2; kf++) {
      bf16x8 a[2], b[4];
#pragma unroll
      for (int m = 0; m < 2; m++) a[m] = *(const bf16x8*)&As[(wr + m * 16 + fr) * 64 + kf * 32 + fg8];
#pragma unroll
      for (int n = 0; n < 4; n++) b[n] = *(const bf16x8*)&Bs[(n * 16 + fr) * 64 + kf * 32 + fg8];
#pragma unroll
      for (int m = 0; m < 2; m++)
#pragma unroll
        for (int n = 0; n < 4; n++)
          acc[m][n] = __builtin_amdgcn_mfma_f32_16x16x32_bf16(a[m], b[n], acc[m][n], 0, 0, 0);
    }
  }

  const int fg4 = (lane >> 4) * 4;
#pragma unroll
  for (int m = 0; m < 2; m++) {
#pragma unroll
    for (int n = 0; n < 4; n++) {
      int col = o0 + n * 16 + fr;
      float bv = bias[col];
#pragma unroll
      for (int r = 0; r < 4; r++) {
        int row = n0 + wr + m * 16 + fg4 + r;
        float v = acc[m][n][r] + bv + res[(size_t)row * O + col];
        out[(size_t)row * O + col] = v;
      }
    }
  }
}

// ---------------------------------------------------------------- flash attention, kv-split x2
__launch_bounds__(512, 4)
__global__ void attn_kernel(const bf16* __restrict__ qkv, const bf16* __restrict__ vt,
                            const float* __restrict__ bias, float* __restrict__ opart,
                            float* __restrict__ ml) {
  __shared__ bf16 Ks[2][64][104];
  __shared__ bf16 Vs[2][96][72];
  __shared__ bf16 Pl[8][16][72];
  const int t    = threadIdx.x;
  const int lane = t & 63;
  const int wave = t >> 6;
  const int qb = blockIdx.x, h = blockIdx.y;
  const int half = blockIdx.z & 1, b = blockIdx.z >> 1;
  const int kvstart = half * 1024;
  const int q0 = qb * 128 + wave * 16;
  const int fq = lane & 15;
  const int g  = lane >> 4;
  const size_t base = (size_t)b * 2048 * 2304;

  bf16x8 qf[3];
  {
    const bf16* qp = qkv + base + (size_t)(q0 + fq) * 2304 + h * 96;
#pragma unroll
    for (int f = 0; f < 3; f++) qf[f] = *(const bf16x8*)(qp + f * 32 + g * 8);
  }

  const int kr1 = t >> 3, kc1 = (t & 7) * 8;
  const int kr2 = t >> 2, kc2 = 64 + (t & 3) * 8;
  const int vr2 = 64 + (t >> 3);
  const bf16* kbase = qkv + base + (size_t)kvstart * 2304 + 768 + h * 96;
  const bf16* vbase = vt + (size_t)((b * 8 + h) * 96) * 2048 + kvstart;

  bf16x8 kreg0, kreg1, vreg0, vreg1;
  const bool lo = (t < 256);

  kreg0 = *(const bf16x8*)(kbase + (size_t)kr1 * 2304 + kc1);
  vreg0 = *(const bf16x8*)(vbase + (size_t)kr1 * 2048 + kc1);
  if (lo) {
    kreg1 = *(const bf16x8*)(kbase + (size_t)kr2 * 2304 + kc2);
    vreg1 = *(const bf16x8*)(vbase + (size_t)vr2 * 2048 + kc1);
  }

  float m_run = -1e30f, l_run = 0.f;
  f32x4 zero = {0.f, 0.f, 0.f, 0.f};
  f32x4 o_acc[6];
#pragma unroll
  for (int i = 0; i < 6; i++) o_acc[i] = zero;

  const float scale = 0.10206207261596575f;  // 1/sqrt(96)
  const float* bp = bias + ((size_t)b * 2048 + q0 + fq) * 2048 + kvstart;

  int cur = 0;
  for (int kv0 = 0; kv0 < 1024; kv0 += 64) {
    *(bf16x8*)&Ks[cur][kr1][kc1] = kreg0;
    *(bf16x8*)&Vs[cur][kr1][kc1] = vreg0;
    if (lo) {
      *(bf16x8*)&Ks[cur][kr2][kc2] = kreg1;
      *(bf16x8*)&Vs[cur][vr2][kc1] = vreg1;
    }
    __syncthreads();

    if (kv0 + 64 < 1024) {
      int nx = kv0 + 64;
      kreg0 = *(const bf16x8*)(kbase + (size_t)(nx + kr1) * 2304 + kc1);
      vreg0 = *(const bf16x8*)(vbase + (size_t)kr1 * 2048 + nx + kc1);
      if (lo) {
        kreg1 = *(const bf16x8*)(kbase + (size_t)(nx + kr2) * 2304 + kc2);
        vreg1 = *(const bf16x8*)(vbase + (size_t)vr2 * 2048 + nx + kc1);
      }
    }
    __builtin_amdgcn_sched_barrier(0);  // pin prefetch issue here

    float4 bf[4];
#pragma unroll
    for (int kvt = 0; kvt < 4; kvt++)
      bf[kvt] = *(const float4*)(bp + kv0 + kvt * 16 + g * 4);

    f32x4 s[4];
#pragma unroll
    for (int kvt = 0; kvt < 4; kvt++) {
      s[kvt] = zero;
#pragma unroll
      for (int f = 0; f < 3; f++) {
        bf16x8 kfr = *(const bf16x8*)&Ks[cur][kvt * 16 + fq][f * 32 + g * 8];
        s[kvt] = __builtin_amdgcn_mfma_f32_16x16x32_bf16(kfr, qf[f], s[kvt], 0, 0, 0);
      }
    }

    float p[4][4];
    float vmax = -1e30f;
#pragma unroll
    for (int kvt = 0; kvt < 4; kvt++) {
#pragma unroll
      for (int r = 0; r < 4; r++) {
        float sv = fmaf(s[kvt][r], scale, (&bf[kvt].x)[r]);
        p[kvt][r] = sv;
        vmax = fmaxf(vmax, sv);
      }
    }
    vmax = fmaxf(vmax, __shfl_xor(vmax, 16));
    vmax = fmaxf(vmax, __shfl_xor(vmax, 32));
    if (!__all(vmax <= m_run + 8.0f)) {
      float m_new = fmaxf(m_run, vmax);
      float corr = exp2f((m_run - m_new) * LOG2E);
      l_run *= corr;
#pragma unroll
      for (int i = 0; i < 6; i++)
#pragma unroll
        for (int r = 0; r < 4; r++) o_acc[i][r] *= corr;
      m_run = m_new;
    }
    float rsum = 0.f;
#pragma unroll
    for (int kvt = 0; kvt < 4; kvt++) {
      bf16x4 pb;
#pragma unroll
      for (int r = 0; r < 4; r++) {
        float pv = exp2f((p[kvt][r] - m_run) * LOG2E);
        rsum += pv;
        pb[r] = (bf16)pv;
      }
      *(bf16x4*)&Pl[wave][fq][kvt * 16 + g * 4] = pb;
    }
    rsum += __shfl_xor(rsum, 16);
    rsum += __shfl_xor(rsum, 32);
    l_run += rsum;

#pragma unroll
    for (int kf = 0; kf < 2; kf++) {
      bf16x8 pfrag = *(const bf16x8*)&Pl[wave][fq][kf * 32 + g * 8];
#pragma unroll
      for (int ht = 0; ht < 6; ht++) {
        bf16x8 vfrag = *(const bf16x8*)&Vs[cur][ht * 16 + fq][kf * 32 + g * 8];
        o_acc[ht] = __builtin_amdgcn_mfma_f32_16x16x32_bf16(vfrag, pfrag, o_acc[ht], 0, 0, 0);
      }
    }
    cur ^= 1;
  }

  float* op = opart + (size_t)half * (16 * 2048 * 96) + ((size_t)(b * 8 + h) * 2048 + q0 + fq) * 96;
  float* mlp = ml + ((size_t)half * 32768 + (size_t)(b * 8 + h) * 2048 + q0 + fq) * 2;
#pragma unroll
  for (int ht = 0; ht < 6; ht++)
    *(f32x4*)&op[ht * 16 + g * 4] = o_acc[ht];
  if (g == 0) { mlp[0] = m_run; mlp[1] = l_run; }
}

// ---------------------------------------------------------------- combine kv-split partials -> ctx bf16
__launch_bounds__(256)
__global__ void attn_combine_kernel(const float* __restrict__ opart, const float* __restrict__ ml,
                                    bf16* __restrict__ ctx) {
  int idx = blockIdx.x * blockDim.x + threadIdx.x;  // float4 id, total 786432
  if (idx >= 786432) return;
  int e = idx * 4;
  int bh = e / (2048 * 96);
  int rem = e - bh * (2048 * 96);
  int q = rem / 96;
  int hd = rem - q * 96;
  const float* op0 = opart;
  const float* op1 = opart + (size_t)16 * 2048 * 96;
  float4 o1 = *(const float4*)&op0[e];
  float4 o2 = *(const float4*)&op1[e];
  const float* ml0 = ml + (size_t)(bh * 2048 + q) * 2;
  const float* ml1 = ml0 + (size_t)32768 * 2;
  float m1 = ml0[0], l1 = ml0[1];
  float m2 = ml1[0], l2 = ml1[1];
  float M = fmaxf(m1, m2);
  float w1 = exp2f((m1 - M) * LOG2E);
  float w2 = exp2f((m2 - M) * LOG2E);
  float inv = 1.0f / (l1 * w1 + l2 * w2);
  int b = bh >> 3, h = bh & 7;
  bf16x4 o;
  o[0] = (bf16)((o1.x * w1 + o2.x * w2) * inv);
  o[1] = (bf16)((o1.y * w1 + o2.y * w2) * inv);
  o[2] = (bf16)((o1.z * w1 + o2.z * w2) * inv);
  o[3] = (bf16)((o1.w * w1 + o2.w * w2) * inv);
  *(bf16x4*)&ctx[((size_t)b * 2048 + q) * 768 + h * 96 + hd] = o;
}

// ---------------------------------------------------------------- LayerNorm (row = block); in may alias outf
__launch_bounds__(256)
__global__ void ln_kernel(const float* in, const float* __restrict__ gamma,
                          const float* __restrict__ beta, float* outf, bf16* outb) {
  const int row = blockIdx.x;
  const int t = threadIdx.x;
  const float* rp = in + (size_t)row * 768;
  float v[3];
#pragma unroll
  for (int i = 0; i < 3; i++) v[i] = rp[t + 256 * i];
  float s = v[0] + v[1] + v[2];
  float ss = v[0] * v[0] + v[1] * v[1] + v[2] * v[2];
#pragma unroll
  for (int off = 1; off < 64; off <<= 1) {
    s += __shfl_xor(s, off);
    ss += __shfl_xor(ss, off);
  }
  __shared__ float red[8];
  if ((t & 63) == 0) { red[(t >> 6) * 2] = s; red[(t >> 6) * 2 + 1] = ss; }
  __syncthreads();
  s = red[0] + red[2] + red[4] + red[6];
  ss = red[1] + red[3] + red[5] + red[7];
  float mu = s * (1.0f / 768.0f);
  float var = ss * (1.0f / 768.0f) - mu * mu;
  float rs = rsqrtf(var + 1e-5f);
#pragma unroll
  for (int i = 0; i < 3; i++) {
    int col = t + 256 * i;
    float y = (v[i] - mu) * rs * gamma[col] + beta[col];
    outf[(size_t)row * 768 + col] = y;
    if (outb) outb[(size_t)row * 768 + col] = (bf16)y;
  }
}

// ---------------------------------------------------------------- launch
extern "C" void kernel_launch(void* const* d_in, const int* in_sizes, int n_in,
                              void* d_out, int out_size, void* d_ws, size_t ws_size,
                              hipStream_t stream) {
  (void)in_sizes; (void)n_in; (void)out_size; (void)ws_size;
  const float* x     = (const float*)d_in[0];
  const float* ab    = (const float*)d_in[1];
  const float* w_qkv = (const float*)d_in[2];
  const float* b_qkv = (const float*)d_in[3];
  const float* w_out = (const float*)d_in[4];
  const float* b_out = (const float*)d_in[5];
  const float* W1    = (const float*)d_in[6];
  const float* b1    = (const float*)d_in[7];
  const float* W2    = (const float*)d_in[8];
  const float* b2    = (const float*)d_in[9];
  const float* g1    = (const float*)d_in[10];
  const float* be1   = (const float*)d_in[11];
  const float* g2    = (const float*)d_in[12];
  const float* be2   = (const float*)d_in[13];
  float* outf = (float*)d_out;

  char* p = (char*)d_ws;
  bf16* xb    = (bf16*)p;  p += (size_t)4096 * 768 * 2;
  bf16* qkv   = (bf16*)p;  p += (size_t)4096 * 2304 * 2;
  bf16* ctx   = (bf16*)p;  p += (size_t)4096 * 768 * 2;
  float* x1f  = (float*)p; p += (size_t)4096 * 768 * 4;     // aliased: vt during attn phase
  bf16* x1b   = (bf16*)p;  p += (size_t)4096 * 768 * 2;
  bf16* hbuf  = (bf16*)p;  p += (size_t)4096 * 2048 * 2;
  bf16* wqkvb = (bf16*)p;  p += (size_t)2304 * 768 * 2;
  bf16* woutb = (bf16*)p;  p += (size_t)768 * 768 * 2;
  bf16* w1b   = (bf16*)p;  p += (size_t)2048 * 768 * 2;
  bf16* w2b   = (bf16*)p;  p += (size_t)768 * 2048 * 2;
  float* opart = (float*)p; p += (size_t)2 * 16 * 2048 * 96 * 4;  // 25.2 MB
  float* mlb   = (float*)p; p += (size_t)2 * 32768 * 2 * 4;       // 0.5 MB
  bf16* vtb   = (bf16*)x1f;   // 6.3MB <= 12.6MB

  CastSegs segs;
  segs.src[0] = x;     segs.dst[0] = xb;
  segs.src[1] = w_qkv; segs.dst[1] = wqkvb;
  segs.src[2] = w_out; segs.dst[2] = woutb;
  segs.src[3] = W1;    segs.dst[3] = w1b;
  segs.src[4] = W2;    segs.dst[4] = w2b;
  fused_cast_kernel<<<2048, 256, 0, stream>>>(segs);

  // qkv = x @ in_proj_w^T + b ; V part written transposed to vtb
  gemm_kernel<3><<<dim3(18, 32), 256, 0, stream>>>(xb, wqkvb, b_qkv, vtb, qkv, 768, 2304);
  // attention (kv-split x2, f32 bias) + combine
  attn_kernel<<<dim3(16, 8, 4), 512, 0, stream>>>(qkv, vtb, ab, opart, mlb);
  attn_combine_kernel<<<3072, 256, 0, stream>>>(opart, mlb, ctx);
  // res1 = ctx @ out_w^T + out_b + x   (into d_out)
  gemmW_kernel<<<dim3(12, 32), 256, 0, stream>>>(ctx, woutb, b_out, x, outf, 768, 768);
  // x1 = LN(res1)
  ln_kernel<<<4096, 256, 0, stream>>>(outf, g1, be1, x1f, x1b);
  // h = gelu(x1 @ W1^T + b1)
  gemm_kernel<2><<<dim3(16, 32), 256, 0, stream>>>(x1b, w1b, b1, nullptr, hbuf, 768, 2048);
  // res2 = h @ W2^T + b2 + x1   (into d_out)
  gemmW_kernel<<<dim3(12, 32), 256, 0, stream>>>(hbuf, w2b, b2, x1f, outf, 2048, 768);
  // out = LN(res2), in place
  ln_kernel<<<4096, 256, 0, stream>>>(outf, g2, be2, outf, nullptr);
}